// Round 1
// baseline (678.166 us; speedup 1.0000x reference)
//
#include <hip/hip_runtime.h>
#include <math.h>

// ---------------------------------------------------------------------------
// HybridBinaryClassifier360: conv1(3->6,5x5,s2,p1)+relu+maxpool2s1 ->
// conv2(6->15,3x3,s2,p1)+relu+maxpool2s1 -> fc 55815->120->84->1 ->
// RBF kernel vs 10 supports -> sigmoid -> [p, 1-p]
// B=128. All fp32.
// ---------------------------------------------------------------------------

#define BATCH 128

// ---------------- Kernel 1: conv1 + relu + maxpool(2,s1) -------------------
// in:  x [128,3,250,250]; w [6,3,5,5]; b [6]
// out: pool1 [128,6,123,123]
// block: 256 thr computes 16x16 pooled tile (needs 17x17 conv tile,
// 37x37 input tile per channel). grid (8,8,128).
__global__ __launch_bounds__(256) void conv1_pool_kernel(
    const float* __restrict__ x, const float* __restrict__ w,
    const float* __restrict__ bias, float* __restrict__ out) {
  const int b = blockIdx.z;
  const int py0 = blockIdx.y * 16;
  const int px0 = blockIdx.x * 16;
  const int tid = threadIdx.x;

  __shared__ float wlds[450];
  __shared__ float blds[6];
  __shared__ float in_lds[3 * 37 * 44];    // stride 44 so strip over-reads stay in-bounds
  __shared__ float conv_lds[6 * 17 * 18];

  for (int i = tid; i < 450; i += 256) wlds[i] = w[i];
  if (tid < 6) blds[tid] = bias[tid];

  const int ih0 = 2 * py0 - 1;
  const int iw0 = 2 * px0 - 1;
  for (int i = tid; i < 3 * 37 * 37; i += 256) {
    int ci = i / (37 * 37);
    int rem = i % (37 * 37);
    int r = rem / 37, c = rem % 37;
    int ih = ih0 + r, iw = iw0 + c;
    float v = 0.f;
    if (ih >= 0 && ih < 250 && iw >= 0 && iw < 250)
      v = x[((b * 3 + ci) * 250 + ih) * 250 + iw];
    in_lds[(ci * 37 + r) * 44 + c] = v;
  }
  __syncthreads();

  // conv strips of 4 consecutive output cols
  for (int s = tid; s < 6 * 17 * 5; s += 256) {
    int oc = s / 85;
    int rem = s % 85;
    int r = rem / 5;
    int c0 = (rem % 5) * 4;
    float acc0 = blds[oc], acc1 = acc0, acc2 = acc0, acc3 = acc0;
    for (int ci = 0; ci < 3; ci++) {
#pragma unroll
      for (int kh = 0; kh < 5; kh++) {
        const float* row = &in_lds[(ci * 37 + 2 * r + kh) * 44 + 2 * c0];
        const float* wr = &wlds[((oc * 3 + ci) * 5 + kh) * 5];
        float v[11];
#pragma unroll
        for (int t = 0; t < 11; t++) v[t] = row[t];
#pragma unroll
        for (int kw = 0; kw < 5; kw++) {
          float wv = wr[kw];
          acc0 += wv * v[kw];
          acc1 += wv * v[2 + kw];
          acc2 += wv * v[4 + kw];
          acc3 += wv * v[6 + kw];
        }
      }
    }
    acc0 = fmaxf(acc0, 0.f); acc1 = fmaxf(acc1, 0.f);
    acc2 = fmaxf(acc2, 0.f); acc3 = fmaxf(acc3, 0.f);
    int base = (oc * 17 + r) * 18;
    conv_lds[base + c0] = acc0;
    if (c0 + 1 < 17) conv_lds[base + c0 + 1] = acc1;
    if (c0 + 2 < 17) conv_lds[base + c0 + 2] = acc2;
    if (c0 + 3 < 17) conv_lds[base + c0 + 3] = acc3;
  }
  __syncthreads();

  for (int i = tid; i < 6 * 16 * 16; i += 256) {
    int oc = i / 256;
    int rem = i % 256;
    int r = rem / 16, c = rem % 16;
    int py = py0 + r, px = px0 + c;
    if (py < 123 && px < 123) {
      int base = (oc * 17 + r) * 18 + c;
      float m = fmaxf(fmaxf(conv_lds[base], conv_lds[base + 1]),
                      fmaxf(conv_lds[base + 18], conv_lds[base + 19]));
      out[((b * 6 + oc) * 123 + py) * 123 + px] = m;
    }
  }
}

// ---------------- Kernel 2: conv2 + relu + maxpool(2,s1) -------------------
// in:  pool1 [128,6,123,123]; w [15,6,3,3]; b [15]
// out: act [128, 15*61*61 = 55815]  (NCHW flatten)
__global__ __launch_bounds__(256) void conv2_pool_kernel(
    const float* __restrict__ in, const float* __restrict__ w,
    const float* __restrict__ bias, float* __restrict__ out) {
  const int b = blockIdx.z;
  const int py0 = blockIdx.y * 16;
  const int px0 = blockIdx.x * 16;
  const int tid = threadIdx.x;

  __shared__ float wlds[810];
  __shared__ float blds[15];
  __shared__ float in_lds[6 * 35 * 42];
  __shared__ float conv_lds[15 * 17 * 18];

  for (int i = tid; i < 810; i += 256) wlds[i] = w[i];
  if (tid < 15) blds[tid] = bias[tid];

  const int ih0 = 2 * py0 - 1;
  const int iw0 = 2 * px0 - 1;
  for (int i = tid; i < 6 * 35 * 35; i += 256) {
    int ci = i / 1225;
    int rem = i % 1225;
    int r = rem / 35, c = rem % 35;
    int ih = ih0 + r, iw = iw0 + c;
    float v = 0.f;
    if (ih >= 0 && ih < 123 && iw >= 0 && iw < 123)
      v = in[((b * 6 + ci) * 123 + ih) * 123 + iw];
    in_lds[(ci * 35 + r) * 42 + c] = v;
  }
  __syncthreads();

  for (int s = tid; s < 15 * 17 * 5; s += 256) {
    int oc = s / 85;
    int rem = s % 85;
    int r = rem / 5;
    int c0 = (rem % 5) * 4;
    float acc0 = blds[oc], acc1 = acc0, acc2 = acc0, acc3 = acc0;
    for (int ci = 0; ci < 6; ci++) {
#pragma unroll
      for (int kh = 0; kh < 3; kh++) {
        const float* row = &in_lds[(ci * 35 + 2 * r + kh) * 42 + 2 * c0];
        const float* wr = &wlds[((oc * 6 + ci) * 3 + kh) * 3];
        float v[9];
#pragma unroll
        for (int t = 0; t < 9; t++) v[t] = row[t];
#pragma unroll
        for (int kw = 0; kw < 3; kw++) {
          float wv = wr[kw];
          acc0 += wv * v[kw];
          acc1 += wv * v[2 + kw];
          acc2 += wv * v[4 + kw];
          acc3 += wv * v[6 + kw];
        }
      }
    }
    acc0 = fmaxf(acc0, 0.f); acc1 = fmaxf(acc1, 0.f);
    acc2 = fmaxf(acc2, 0.f); acc3 = fmaxf(acc3, 0.f);
    int base = (oc * 17 + r) * 18;
    conv_lds[base + c0] = acc0;
    if (c0 + 1 < 17) conv_lds[base + c0 + 1] = acc1;
    if (c0 + 2 < 17) conv_lds[base + c0 + 2] = acc2;
    if (c0 + 3 < 17) conv_lds[base + c0 + 3] = acc3;
  }
  __syncthreads();

  for (int i = tid; i < 15 * 16 * 16; i += 256) {
    int oc = i / 256;
    int rem = i % 256;
    int r = rem / 16, c = rem % 16;
    int py = py0 + r, px = px0 + c;
    if (py < 61 && px < 61) {
      int base = (oc * 17 + r) * 18 + c;
      float m = fmaxf(fmaxf(conv_lds[base], conv_lds[base + 1]),
                      fmaxf(conv_lds[base + 18], conv_lds[base + 19]));
      out[((b * 15 + oc) * 61 + py) * 61 + px] = m;
    }
  }
}

// ---------------- Kernel 3: fc1 split-K GEMM partials ----------------------
// C[128,120] = act[128,55815] @ fc1_w[120,55815]^T
// Each block: K-chunk of 256, full 128x120(->128) tile, partial to ws.
#define KTOT 55815
#define NPART 219   // ceil(55815/256)
__global__ __launch_bounds__(256) void fc1_splitk_kernel(
    const float* __restrict__ act, const float* __restrict__ w,
    float* __restrict__ partial) {
  const int kbase = blockIdx.x * 256;
  const int tid = threadIdx.x;
  const int tx = tid % 16, ty = tid / 16;
  __shared__ float ldsA[8 * 132];
  __shared__ float ldsB[8 * 132];
  float acc[8][8];
#pragma unroll
  for (int i = 0; i < 8; i++)
#pragma unroll
    for (int j = 0; j < 8; j++) acc[i][j] = 0.f;

  for (int s8 = 0; s8 < 32; s8++) {
    int kofs = kbase + s8 * 8;
    __syncthreads();
    for (int i = tid; i < 1024; i += 256) {       // A: 128 rows x 8 k
      int m = i >> 3, kk = i & 7;
      int k = kofs + kk;
      ldsA[kk * 132 + m] = (k < KTOT) ? act[m * KTOT + k] : 0.f;
    }
    for (int i = tid; i < 960; i += 256) {        // B: 120 cols x 8 k
      int n = i >> 3, kk = i & 7;
      int k = kofs + kk;
      ldsB[kk * 132 + n] = (k < KTOT) ? w[n * KTOT + k] : 0.f;
    }
    __syncthreads();
#pragma unroll
    for (int kk = 0; kk < 8; kk++) {
      float4 a0 = *(const float4*)&ldsA[kk * 132 + ty * 8];
      float4 a1 = *(const float4*)&ldsA[kk * 132 + ty * 8 + 4];
      float4 b0 = *(const float4*)&ldsB[kk * 132 + tx * 8];
      float4 b1 = *(const float4*)&ldsB[kk * 132 + tx * 8 + 4];
      float av[8] = {a0.x, a0.y, a0.z, a0.w, a1.x, a1.y, a1.z, a1.w};
      float bv[8] = {b0.x, b0.y, b0.z, b0.w, b1.x, b1.y, b1.z, b1.w};
#pragma unroll
      for (int i = 0; i < 8; i++)
#pragma unroll
        for (int j = 0; j < 8; j++) acc[i][j] += av[i] * bv[j];
    }
  }

  float* dst = partial + (size_t)blockIdx.x * 15360;
#pragma unroll
  for (int i = 0; i < 8; i++) {
    int row = ty * 8 + i;
#pragma unroll
    for (int j = 0; j < 8; j++) {
      int col = tx * 8 + j;
      if (col < 120) dst[row * 120 + col] = acc[i][j];
    }
  }
}

// ---------------- Kernel 4: reduce partials + bias + relu ------------------
__global__ __launch_bounds__(256) void fc1_reduce_kernel(
    const float* __restrict__ partial, const float* __restrict__ bias,
    float* __restrict__ h1) {
  int idx = blockIdx.x * 256 + threadIdx.x;
  if (idx >= 15360) return;
  float s = 0.f;
  for (int p = 0; p < NPART; p++) s += partial[(size_t)p * 15360 + idx];
  h1[idx] = fmaxf(s + bias[idx % 120], 0.f);
}

// ---------------- Kernel 5: fc2 + fc3 + RBF + sigmoid ----------------------
__global__ __launch_bounds__(128) void head_kernel(
    const float* __restrict__ h1, const float* __restrict__ fc2_w,
    const float* __restrict__ fc2_b, const float* __restrict__ fc3_w,
    const float* __restrict__ fc3_b, const float* __restrict__ support,
    float* __restrict__ out) {
  int b = blockIdx.x, t = threadIdx.x;
  __shared__ float hrow[120];
  __shared__ float s2[84];
  if (t < 120) hrow[t] = h1[b * 120 + t];
  __syncthreads();
  if (t < 84) {
    float d = fc2_b[t];
    for (int k = 0; k < 120; k++) d += fc2_w[t * 120 + k] * hrow[k];
    s2[t] = fmaxf(d, 0.f);
  }
  __syncthreads();
  if (t == 0) {
    float h = fc3_b[0];
    for (int j = 0; j < 84; j++) h += fc3_w[j] * s2[j];
    float ks = 0.f;
    for (int j = 0; j < 10; j++) {
      float diff = h - support[j];
      ks += expf(-diff * diff);
    }
    ks *= 0.1f;
    float p = 1.f / (1.f + expf(-ks));
    out[b * 2] = p;
    out[b * 2 + 1] = 1.f - p;
  }
}

// ---------------------------------------------------------------------------
extern "C" void kernel_launch(void* const* d_in, const int* in_sizes, int n_in,
                              void* d_out, int out_size, void* d_ws, size_t ws_size,
                              hipStream_t stream) {
  const float* x   = (const float*)d_in[0];
  const float* c1w = (const float*)d_in[1];
  const float* c1b = (const float*)d_in[2];
  const float* c2w = (const float*)d_in[3];
  const float* c2b = (const float*)d_in[4];
  const float* f1w = (const float*)d_in[5];
  const float* f1b = (const float*)d_in[6];
  const float* f2w = (const float*)d_in[7];
  const float* f2b = (const float*)d_in[8];
  const float* f3w = (const float*)d_in[9];
  const float* f3b = (const float*)d_in[10];
  const float* sup = (const float*)d_in[11];
  float* out = (float*)d_out;

  char* ws = (char*)d_ws;
  // ws layout (bytes):
  //   pool1: 128*6*123*123*4          = 46,476,288
  //   act:   128*55815*4              = 28,577,280   @ 46,476,288
  //   part:  219*15360*4              = 13,455,360   @ 75,053,568
  //   h1:    15360*4                  =     61,440   @ 88,508,928
  float* pool1 = (float*)ws;
  float* act   = (float*)(ws + 46476288);
  float* part  = (float*)(ws + 75053568);
  float* h1    = (float*)(ws + 88508928);

  conv1_pool_kernel<<<dim3(8, 8, BATCH), 256, 0, stream>>>(x, c1w, c1b, pool1);
  conv2_pool_kernel<<<dim3(4, 4, BATCH), 256, 0, stream>>>(pool1, c2w, c2b, act);
  fc1_splitk_kernel<<<NPART, 256, 0, stream>>>(act, f1w, part);
  fc1_reduce_kernel<<<60, 256, 0, stream>>>(part, f1b, h1);
  head_kernel<<<BATCH, 128, 0, stream>>>(h1, f2w, f2b, f3w, f3b, sup, out);
}